// Round 8
// baseline (264.073 us; speedup 1.0000x reference)
//
#include <hip/hip_runtime.h>
#include <cstddef>
#include <cstdint>

// ---------------------------------------------------------------------------
// Pipeline: x (64,3,64,64) -> conv1 5x5s2 (MFMA polyphase) -> GDN1 (MFMA)
//   -> conv2 5x5s2 (MFMA polyphase) -> GDN2 (MFMA) -> conv3 3x3 (MFMA, bf16)
//   -> LN -> QKV proj (MFMA, bf16 out) -> Bahdanau attention
//   -> fused outproj+LN+transpose.  10 launches.
// ---------------------------------------------------------------------------

typedef __bf16 bf16x8 __attribute__((ext_vector_type(8)));
typedef float floatx4 __attribute__((ext_vector_type(4)));
typedef unsigned short ushortT;
typedef unsigned short ushort8v __attribute__((ext_vector_type(8)));

#if __has_builtin(__builtin_amdgcn_exp2f)
#define EXP2F(x) __builtin_amdgcn_exp2f(x)
#else
#define EXP2F(x) exp2f(x)
#endif
#if __has_builtin(__builtin_amdgcn_rcpf)
#define RCPF(x) __builtin_amdgcn_rcpf(x)
#else
#define RCPF(x) (1.f / (x))
#endif

__device__ __forceinline__ ushortT f2bf(float f) {
  unsigned u = __builtin_bit_cast(unsigned, f);
  unsigned r = (u + 0x7FFFu + ((u >> 16) & 1u)) >> 16;
  return (ushortT)r;
}
__device__ __forceinline__ float bf2f(ushortT u) {
  return __builtin_bit_cast(float, ((unsigned)u) << 16);
}

// ---- workspace layout (float-slot offsets) ----
static constexpr size_t OFF_T1BF = 0;          // conv1 out bf16 (64,1024,128)
static constexpr size_t OFF_X2BF = 4194304;    // gdn1 out bf16 [b][4][256][128]
static constexpr size_t OFF_T2BF = 8388608;    // conv2 out bf16 (64,256,128)
static constexpr size_t OFF_X3BF = 9437184;    // gdn2 out bf16 (64,256,128)
static constexpr size_t OFF_QRAW = 10485760;   // conv3 out bf16 (64,256,192)
static constexpr size_t OFF_QLNB = 16777216;   // bf16 (64,256,192)
static constexpr size_t OFF_KVB  = 18350080;   // bf16 (64,32,192)
static constexpr size_t OFF_QP   = 18546688;   // bf16 (64,256,128)
static constexpr size_t OFF_KP   = 20643840;   // bf16 (64,32,128)
static constexpr size_t OFF_VP   = 20905984;   // bf16 (64,32,192)
static constexpr size_t OFF_WBQ  = 21299200;   // bf16 128x192 (scaled by c)
static constexpr size_t OFF_WBK  = 21311488;   // bf16 128x192 (scaled by c)
static constexpr size_t OFF_WBV  = 21323776;   // bf16 192x192
static constexpr size_t OFF_WBO  = 21342208;   // bf16 192x192
static constexpr size_t OFF_CTXB = 21360640;   // bf16 (64,256,192)
static constexpr size_t OFF_WT2  = 26079232;   // bf16 conv2 slabs [200][2048]
static constexpr size_t OFF_WT3  = 26284032;   // bf16 conv3 slabs [108][2048]
static constexpr size_t OFF_WC1  = 26394624;   // bf16 conv1 slabs [5][128][32]
static constexpr size_t OFF_GB1  = 26406912;   // bf16 gamma1 128x128
static constexpr size_t OFF_GB2  = 26415104;   // bf16 gamma2 128x128

// 5x5 s2 p2 polyphase tap tables (tap id = kh*5+kw); HW-verified via conv2.
__device__ __constant__ int d_TWI2[4][9] = {{ 0, 2, 4,10,12,14,20,22,24},
                                            { 1, 3,11,13,21,23, 0, 0, 0},
                                            { 5, 7, 9,15,17,19, 0, 0, 0},
                                            { 6, 8,16,18, 0, 0, 0, 0, 0}};
__device__ __constant__ int d_NT2[4] = {9, 6, 6, 4};

// ---------------------------------------------------------------------------
// fused prep: all weight repacks/casts in one launch, block-range dispatch.
// ---------------------------------------------------------------------------
__device__ void dev_convw3(const float* w, ushortT* wt, int mode, int total,
                           int idx) {
  if (idx >= total) return;
  int j    = idx & 7;
  int om   = (idx >> 3) & 63;
  int kg   = (idx >> 9) & 3;
  int slab = idx >> 11;
  int mt, s, tap, T;
  if (mode == 0) {
    int ph;
    if (slab < 72) ph = 0; else if (slab < 120) ph = 1;
    else if (slab < 168) ph = 2; else ph = 3;
    const int st[4] = {0, 72, 120, 168};
    const int ns[4] = {36, 24, 24, 16};
    int rel = slab - st[ph];
    mt = rel / ns[ph]; s = rel % ns[ph];
    tap = d_TWI2[ph][s >> 2]; T = 25;
  } else {
    mt = slab / 36; s = slab % 36; tap = s >> 2; T = 9;
  }
  int cc = s & 3;
  int c  = cc * 32 + kg * 8 + j;
  int oc = mt * 64 + om;
  wt[idx] = f2bf(w[(size_t)(oc * 128 + c) * T + tap]);
}

__device__ void dev_convw1(const float* w, ushortT* wt, int idx) {
  if (idx >= 20480) return;
  int k    = idx & 31;
  int oc   = (idx >> 5) & 127;
  int slab = idx >> 12;
  int ph, i;
  if (slab < 2) { ph = 0; i = slab; } else { ph = slab - 1; i = 0; }
  int kg = k >> 3, jj = k & 7;
  int tidx = i * 8 + jj;
  float val = 0.f;
  if (kg < 3 && tidx < d_NT2[ph]) {
    int tap = d_TWI2[ph][tidx];
    val = w[(size_t)(oc * 3 + kg) * 25 + tap];
  }
  wt[idx] = f2bf(val);
}

__device__ void dev_wcast(const float* w, ushortT* wb, int total, float scale,
                          int idx) {
  if (idx < total) wb[idx] = f2bf(w[idx] * scale);
}

__global__ __launch_bounds__(256) void prep_kernel(
    const float* __restrict__ conv2_w, ushortT* __restrict__ wt2,
    const float* __restrict__ conv3_w, ushortT* __restrict__ wt3,
    const float* __restrict__ conv1_w, ushortT* __restrict__ wc1,
    const float* __restrict__ Wq, ushortT* __restrict__ wbq,
    const float* __restrict__ Wk, ushortT* __restrict__ wbk,
    const float* __restrict__ Wv, ushortT* __restrict__ wbv,
    const float* __restrict__ out_w, ushortT* __restrict__ wbo,
    const float* __restrict__ gamma1, ushortT* __restrict__ gb1,
    const float* __restrict__ gamma2, ushortT* __restrict__ gb2) {
  constexpr float C2LE = 2.88539008177792681f;   // 2*log2(e)
  int blk = blockIdx.x, tid = threadIdx.x;
  if (blk < 1600)      dev_convw3(conv2_w, wt2, 0, 409600, blk * 256 + tid);
  else if (blk < 2464) dev_convw3(conv3_w, wt3, 1, 221184, (blk - 1600) * 256 + tid);
  else if (blk < 2544) dev_convw1(conv1_w, wc1, (blk - 2464) * 256 + tid);
  else if (blk < 2640) dev_wcast(Wq, wbq, 24576, C2LE, (blk - 2544) * 256 + tid);
  else if (blk < 2736) dev_wcast(Wk, wbk, 24576, C2LE, (blk - 2640) * 256 + tid);
  else if (blk < 2880) dev_wcast(Wv, wbv, 36864, 1.f, (blk - 2736) * 256 + tid);
  else if (blk < 3024) dev_wcast(out_w, wbo, 36864, 1.f, (blk - 2880) * 256 + tid);
  else if (blk < 3088) dev_wcast(gamma1, gb1, 16384, 1.f, (blk - 3024) * 256 + tid);
  else                 dev_wcast(gamma2, gb2, 16384, 1.f, (blk - 3088) * 256 + tid);
}

// ---------------------------------------------------------------------------
// conv1 MFMA polyphase: (64,3,64,64) fp32 -> (64,1024px,128c) bf16.
// ---------------------------------------------------------------------------
__global__ __launch_bounds__(256, 1) void conv1_mfma_kernel(
    const float* __restrict__ x, const ushortT* __restrict__ wc1,
    const float* __restrict__ bias, ushortT* __restrict__ outb) {
  int b  = blockIdx.x >> 2;
  int yg = blockIdx.x & 3;
  int y0 = yg * 8;

  int wave = threadIdx.x >> 6;
  int lane = threadIdx.x & 63;
  int ln15 = lane & 15;
  int kg   = lane >> 4;
  int tid  = threadIdx.x;

  __shared__ ushortT simg[4680];
  __shared__ ushortT sA[5 * 128 * 40];

  for (int j = tid; j < 2340; j += 256) ((unsigned*)simg)[j] = 0u;
  __syncthreads();

  int ihBase = 2 * y0 - 2;
  const float* xb = x + (size_t)b * 3 * 4096;
  for (int j = tid; j < 960; j += 256) {
    int q = j & 15;
    int rr = j >> 4;
    int c = rr / 20, ihl = rr % 20;
    int ih = ihBase + ihl;
    if (ih >= 0 && ih < 64) {
      float4 v = *(const float4*)&xb[c * 4096 + ih * 64 + q * 4];
      int pr = ih & 1, u = ih >> 1;
      int lr = u - y0 + 1;
      int base0 = ((pr * 2 + 0) * 3 + c) * 360 + lr * 36;
      int base1 = ((pr * 2 + 1) * 3 + c) * 360 + lr * 36;
      simg[base0 + 2 * q + 1] = f2bf(v.x);
      simg[base1 + 2 * q + 1] = f2bf(v.y);
      simg[base0 + 2 * q + 2] = f2bf(v.z);
      simg[base1 + 2 * q + 2] = f2bf(v.w);
    }
  }
  for (int j = tid; j < 2560; j += 256) {
    int chunk = j & 3, row = j >> 2;
    uint4 v = *(const uint4*)&wc1[row * 32 + chunk * 8];
    *(uint4*)&sA[row * 40 + chunk * 8] = v;
  }
  __syncthreads();

  constexpr int TDR[4][9] = {{-1,-1,-1, 0, 0, 0, 1, 1, 1},
                             {-1,-1, 0, 0, 1, 1, 0, 0, 0},
                             {-1,-1,-1, 0, 0, 0, 0, 0, 0},
                             {-1,-1, 0, 0, 0, 0, 0, 0, 0}};
  constexpr int TDC[4][9] = {{-1, 0, 1,-1, 0, 1,-1, 0, 1},
                             {-1, 0,-1, 0,-1, 0, 0, 0, 0},
                             {-1, 0, 1,-1, 0, 1, 0, 0, 0},
                             {-1, 0,-1, 0, 0, 0, 0, 0, 0}};
  constexpr int NT[4]  = {9, 6, 6, 4};
  constexpr int NM[4]  = {2, 1, 1, 1};
  constexpr int SB[4]  = {0, 2, 3, 4};

  ushort8v Bf[4][5];
  #pragma unroll
  for (int ntl = 0; ntl < 4; ++ntl) {
    int ntg = wave * 4 + ntl;
    int yloc = ntg >> 1;
    int xx = (ntg & 1) * 16 + ln15;
    int lbase = (yloc + 1) * 36 + xx + 1 + kg * 360;
    #pragma unroll
    for (int ph = 0; ph < 4; ++ph) {
      int pbase = ph * 1080 + lbase;
      #pragma unroll
      for (int i = 0; i < 2; ++i) {
        if (i < NM[ph]) {
          ushort8v bv;
          #pragma unroll
          for (int j = 0; j < 8; ++j) {
            int tidx = i * 8 + j;
            if (tidx >= NT[ph]) tidx = 0;
            int off = TDR[ph][tidx] * 36 + TDC[ph][tidx];
            bv[j] = simg[pbase + off];
          }
          Bf[ntl][SB[ph] + i] = bv;
        }
      }
    }
  }

  #pragma unroll
  for (int m = 0; m < 8; ++m) {
    bf16x8 Af[5];
    #pragma unroll
    for (int s = 0; s < 5; ++s)
      Af[s] = *(const bf16x8*)&sA[(s * 128 + m * 16 + ln15) * 40 + kg * 8];
    int oc0 = m * 16 + kg * 4;
    float4 bv = *(const float4*)&bias[oc0];
    #pragma unroll
    for (int ntl = 0; ntl < 4; ++ntl) {
      floatx4 acc = (floatx4)0.f;
      #pragma unroll
      for (int s = 0; s < 5; ++s)
        acc = __builtin_amdgcn_mfma_f32_16x16x32_bf16(
            Af[s], __builtin_bit_cast(bf16x8, Bf[ntl][s]), acc, 0, 0, 0);
      int ntg = wave * 4 + ntl;
      int y = y0 + (ntg >> 1);
      int xx = (ntg & 1) * 16 + ln15;
      int p = y * 32 + xx;
      ushort4 o4 = {f2bf(acc[0] + bv.x), f2bf(acc[1] + bv.y),
                    f2bf(acc[2] + bv.z), f2bf(acc[3] + bv.w)};
      *(ushort4*)&outb[((size_t)b * 1024 + p) * 128 + oc0] = o4;
    }
  }
}

// ---------------------------------------------------------------------------
// GDN as bf16 MFMA GEMM.
// ---------------------------------------------------------------------------
__global__ __launch_bounds__(256) void gdn_mfma_kernel(
    const ushortT* __restrict__ xbf, const ushortT* __restrict__ gb,
    const float* __restrict__ beta, ushortT* __restrict__ ybf,
    int HW, int nPixTiles, int isSplit) {
  int pt = blockIdx.x % nPixTiles;
  int b  = blockIdx.x / nPixTiles;
  int px0 = pt * 64;
  int tid = threadIdx.x;
  int wave = tid >> 6, lane = tid & 63, ln15 = lane & 15, kg = lane >> 4;

  __shared__ ushortT sG[128 * 136];
  __shared__ ushortT sX[64 * 136];

  for (int j = tid; j < 2048; j += 256) {
    int row = j >> 4, ch = j & 15;
    *(uint4*)&sG[row * 136 + ch * 8] = *(const uint4*)&gb[row * 128 + ch * 8];
  }
  for (int j = tid; j < 1024; j += 256) {
    int row = j >> 4, ch = j & 15;
    ushort8v xv = *(const ushort8v*)&xbf[((size_t)(b * HW + px0 + row)) * 128 + ch * 8];
    ushort8v sq;
    #pragma unroll
    for (int r = 0; r < 8; ++r) {
      float f = bf2f(xv[r]);
      sq[r] = f2bf(f * f);
    }
    *(ushort8v*)&sX[row * 136 + ch * 8] = sq;
  }
  __syncthreads();

  floatx4 acc[2][4];
  #pragma unroll
  for (int mi = 0; mi < 2; ++mi)
    #pragma unroll
    for (int nt = 0; nt < 4; ++nt) acc[mi][nt] = (floatx4)0.f;

  #pragma unroll
  for (int k0 = 0; k0 < 128; k0 += 32) {
    bf16x8 a0 = *(const bf16x8*)&sG[(wave * 32 + ln15) * 136 + k0 + kg * 8];
    bf16x8 a1 = *(const bf16x8*)&sG[(wave * 32 + 16 + ln15) * 136 + k0 + kg * 8];
    #pragma unroll
    for (int nt = 0; nt < 4; ++nt) {
      bf16x8 bb = *(const bf16x8*)&sX[(nt * 16 + ln15) * 136 + k0 + kg * 8];
      acc[0][nt] = __builtin_amdgcn_mfma_f32_16x16x32_bf16(a0, bb, acc[0][nt], 0, 0, 0);
      acc[1][nt] = __builtin_amdgcn_mfma_f32_16x16x32_bf16(a1, bb, acc[1][nt], 0, 0, 0);
    }
  }

  #pragma unroll
  for (int mi = 0; mi < 2; ++mi) {
    int d0 = wave * 32 + mi * 16 + kg * 4;
    float4 bt = *(const float4*)&beta[d0];
    #pragma unroll
    for (int nt = 0; nt < 4; ++nt) {
      int p = px0 + nt * 16 + ln15;
      ushort4 x4 = *(const ushort4*)&xbf[((size_t)(b * HW + p)) * 128 + d0];
      ushort4 o4;
      o4.x = f2bf(bf2f(x4.x) * rsqrtf(acc[mi][nt][0] + bt.x));
      o4.y = f2bf(bf2f(x4.y) * rsqrtf(acc[mi][nt][1] + bt.y));
      o4.z = f2bf(bf2f(x4.z) * rsqrtf(acc[mi][nt][2] + bt.z));
      o4.w = f2bf(bf2f(x4.w) * rsqrtf(acc[mi][nt][3] + bt.w));
      size_t dst;
      if (isSplit) {
        int h = p >> 5, w5 = p & 31;
        int ph = ((h & 1) << 1) | (w5 & 1);
        dst = (((size_t)b * 4 + ph) * 256 + (h >> 1) * 16 + (w5 >> 1)) * 128 + d0;
      } else {
        dst = ((size_t)b * 256 + p) * 128 + d0;
      }
      *(ushort4*)&ybf[dst] = o4;
    }
  }
}

// ---------------------------------------------------------------------------
// conv2/conv3 MFMA implicit GEMM; 4-row split, 2 blocks/CU, bf16 out.
// ---------------------------------------------------------------------------
template<int MODE>
__global__ __launch_bounds__(256, 2) void conv_mfma_kernel(
    const ushortT* __restrict__ X,
    const ushortT* __restrict__ Wt,
    const float* __restrict__ bias,
    ushortT* __restrict__ outb) {
  constexpr int OC  = (MODE == 0) ? 128 : 192;
  constexpr int NMT = OC / 64;
  constexpr int NPH = (MODE == 0) ? 4 : 1;

  int b   = blockIdx.x / (NMT * 4);
  int rem = blockIdx.x % (NMT * 4);
  int mt  = rem >> 2;
  int rs  = rem & 3;
  int r0  = rs * 4;

  int wave = threadIdx.x >> 6;
  int lane = threadIdx.x & 63;
  int ln15 = lane & 15;
  int kg   = lane >> 4;

  __shared__ ushortT simg[6 * 18 * 136];

  floatx4 acc[4];
  #pragma unroll
  for (int m = 0; m < 4; ++m) acc[m] = (floatx4)0.f;

  constexpr int NS2[4]      = {36, 24, 24, 16};
  constexpr int PHSTART2[4] = {0, 72, 120, 168};
  constexpr int TDR_2[4][9] = {{-1,-1,-1, 0, 0, 0, 1, 1, 1},
                               {-1,-1, 0, 0, 1, 1, 0, 0, 0},
                               {-1,-1,-1, 0, 0, 0, 0, 0, 0},
                               {-1,-1, 0, 0, 0, 0, 0, 0, 0}};
  constexpr int TDC_2[4][9] = {{-1, 0, 1,-1, 0, 1,-1, 0, 1},
                               {-1, 0,-1, 0,-1, 0, 0, 0, 0},
                               {-1, 0, 1,-1, 0, 1, 0, 0, 0},
                               {-1, 0,-1, 0, 0, 0, 0, 0, 0}};
  constexpr int TDR_3[9] = {-1,-1,-1, 0, 0, 0, 1, 1, 1};
  constexpr int TDC_3[9] = {-1, 0, 1,-1, 0, 1,-1, 0, 1};

  const int aoff = kg * 512 + ln15 * 8;
  uint4 apf[8][4];

  #pragma unroll
  for (int ph = 0; ph < NPH; ++ph) {
    const int NS = (MODE == 0) ? NS2[ph] : 36;
    const int slabBase = (MODE == 0) ? (PHSTART2[ph] + mt * NS2[ph]) : (mt * 36);
    const ushortT* wp0 = Wt + (size_t)slabBase * 2048 + aoff;

    __syncthreads();
    const ushortT* Xb = X + (((size_t)b * NPH + ph) * 256) * 128;
    for (int idx = threadIdx.x; idx < 1728; idx += 256) {
      int chunk = idx & 15;
      int pix = idx >> 4;
      int row = pix / 18, colm = pix - row * 18;
      int i = r0 - 1 + row, j = colm - 1;
      uint4 v = {0u, 0u, 0u, 0u};
      if (i >= 0 && i < 16 && j >= 0 && j < 16)
        v = *(const uint4*)(Xb + ((size_t)(i * 16 + j)) * 128 + chunk * 8);
      *(uint4*)&simg[(row * 18 + colm) * 136 + chunk * 8] = v;
    }
    #pragma unroll
    for (int jj = 0; jj < 8; ++jj)
      if (jj < NS) {
        #pragma unroll
        for (int m = 0; m < 4; ++m)
          apf[jj][m] = *(const uint4*)(wp0 + (size_t)jj * 2048 + m * 128);
      }
    __syncthreads();

    #pragma unroll
    for (int s0 = 0; s0 < NS; s0 += 8) {
      #pragma unroll
      for (int jj = 0; jj < 8; ++jj) {
        int s = s0 + jj;
        if (s < NS) {
          bf16x8 acur[4];
          #pragma unroll
          for (int m = 0; m < 4; ++m) acur[m] = __builtin_bit_cast(bf16x8, apf[jj][m]);
          int sp = s + 8;
          if (sp < NS) {
            #pragma unroll
            for (int m = 0; m < 4; ++m)
              apf[jj][m] = *(const uint4*)(wp0 + (size_t)sp * 2048 + m * 128);
          }
          int t  = s >> 2;
          int c0 = (s & 3) * 32;
          int dr = (MODE == 0) ? TDR_2[ph][t] : TDR_3[t];
          int dc = (MODE == 0) ? TDC_2[ph][t] : TDC_3[t];
          int lrow = wave + dr + 1;
          int lcol = ln15 + dc + 1;
          bf16x8 bfr = *(const bf16x8*)&simg[(lrow * 18 + lcol) * 136 + c0 + kg * 8];
          #pragma unroll
          for (int m = 0; m < 4; ++m)
            acc[m] = __builtin_amdgcn_mfma_f32_16x16x32_bf16(acur[m], bfr, acc[m], 0, 0, 0);
        }
      }
    }
  }

  #pragma unroll
  for (int m = 0; m < 4; ++m) {
    int mg = mt * 64 + m * 16 + kg * 4;
    float4 bv = *(const float4*)&bias[mg];
    int r = r0 + wave;
    int p = r * 16 + ln15;
    ushort4 o4 = {f2bf(acc[m][0] + bv.x), f2bf(acc[m][1] + bv.y),
                  f2bf(acc[m][2] + bv.z), f2bf(acc[m][3] + bv.w)};
    *(ushort4*)&outb[((size_t)b * 256 + p) * OC + mg] = o4;
  }
}

// ---------------------------------------------------------------------------
// bf16 MFMA GEMM body: C[r][n] = sum_k A[r][k]*B[n][k]; K=192; bf16 out.
// ---------------------------------------------------------------------------
__device__ __forceinline__ void gemm_body(
    const ushortT* A, const ushortT* Bm, ushortT* C,
    int N, int r0, int n0, int tid) {
  __shared__ ushortT sA[128 * 196];
  __shared__ ushortT sB[64 * 196];
  for (int j = tid; j < 3072; j += 256) {
    int row = j / 24, ch = j % 24;
    *(ushort8v*)&sA[row * 196 + ch * 8] = *(const ushort8v*)&A[(size_t)(r0 + row) * 192 + ch * 8];
  }
  for (int j = tid; j < 1536; j += 256) {
    int row = j / 24, ch = j % 24;
    *(ushort8v*)&sB[row * 196 + ch * 8] = *(const ushort8v*)&Bm[(size_t)(n0 + row) * 192 + ch * 8];
  }
  __syncthreads();
  int wave = tid >> 6, lane = tid & 63, ln15 = lane & 15, kg = lane >> 4;
  floatx4 acc[2][4];
  #pragma unroll
  for (int m = 0; m < 2; ++m)
    #pragma unroll
    for (int n = 0; n < 4; ++n) acc[m][n] = (floatx4)0.f;

  #pragma unroll
  for (int k0 = 0; k0 < 192; k0 += 32) {
    bf16x8 afr[2];
    #pragma unroll
    for (int m = 0; m < 2; ++m)
      afr[m] = *(const bf16x8*)&sA[(wave * 32 + m * 16 + ln15) * 196 + k0 + kg * 8];
    #pragma unroll
    for (int n = 0; n < 4; ++n) {
      bf16x8 bfr = *(const bf16x8*)&sB[(n * 16 + ln15) * 196 + k0 + kg * 8];
      acc[0][n] = __builtin_amdgcn_mfma_f32_16x16x32_bf16(afr[0], bfr, acc[0][n], 0, 0, 0);
      acc[1][n] = __builtin_amdgcn_mfma_f32_16x16x32_bf16(afr[1], bfr, acc[1][n], 0, 0, 0);
    }
  }
  #pragma unroll
  for (int n = 0; n < 4; ++n) {
    int col = n0 + n * 16 + ln15;
    #pragma unroll
    for (int m = 0; m < 2; ++m) {
      int rowb = r0 + wave * 32 + m * 16 + kg * 4;
      #pragma unroll
      for (int r = 0; r < 4; ++r)
        C[(size_t)(rowb + r) * N + col] = f2bf(acc[m][n][r]);
    }
  }
}

// fused Q/K/V projection GEMMs in one launch (336 blocks); bf16 outputs.
__global__ __launch_bounds__(256) void gemm_qkv_kernel(
    const ushortT* __restrict__ qlnb, const ushortT* __restrict__ kvb,
    const ushortT* __restrict__ wbq, const ushortT* __restrict__ wbk,
    const ushortT* __restrict__ wbv,
    ushortT* __restrict__ qpb, ushortT* __restrict__ kpb,
    ushortT* __restrict__ vpb) {
  int blk = blockIdx.x, tid = threadIdx.x;
  if (blk < 256) {
    gemm_body(qlnb, wbq, qpb, 128, (blk >> 1) * 128, (blk & 1) * 64, tid);
  } else if (blk < 288) {
    int k = blk - 256;
    gemm_body(kvb, wbk, kpb, 128, (k >> 1) * 128, (k & 1) * 64, tid);
  } else {
    int k = blk - 288;
    gemm_body(kvb, wbv, vpb, 192, (k / 3) * 128, (k % 3) * 64, tid);
  }
}

// ---------------------------------------------------------------------------
// fused LN: blocks [0,4096) -> LN(qrawb bf16) -> qlnb bf16;
//           blocks [4096,4608) -> LN(y_g gather) -> kvb bf16.
// ---------------------------------------------------------------------------
__global__ __launch_bounds__(256) void ln_all_kernel(
    const ushortT* __restrict__ qrawb, const float* __restrict__ qw,
    const float* __restrict__ qb, ushortT* __restrict__ qlnb,
    const float* __restrict__ yg, const float* __restrict__ kw,
    const float* __restrict__ kb, ushortT* __restrict__ kvb) {
  int lane = threadIdx.x & 63;
  if (blockIdx.x < 4096) {
    int row = blockIdx.x * 4 + (threadIdx.x >> 6);
    const ushortT* xr = qrawb + (size_t)row * 192;
    float v0 = bf2f(xr[lane]), v1 = bf2f(xr[lane + 64]), v2 = bf2f(xr[lane + 128]);
    float s = v0 + v1 + v2;
    float s2 = v0 * v0 + v1 * v1 + v2 * v2;
    #pragma unroll
    for (int off = 32; off; off >>= 1) { s += __shfl_xor(s, off); s2 += __shfl_xor(s2, off); }
    float mean = s * (1.f / 192.f);
    float var = s2 * (1.f / 192.f) - mean * mean;
    float inv = rsqrtf(var + 1e-5f);
    ushortT* ybr = qlnb + (size_t)row * 192;
    ybr[lane]       = f2bf((v0 - mean) * inv * qw[lane]       + qb[lane]);
    ybr[lane + 64]  = f2bf((v1 - mean) * inv * qw[lane + 64]  + qb[lane + 64]);
    ybr[lane + 128] = f2bf((v2 - mean) * inv * qw[lane + 128] + qb[lane + 128]);
  } else {
    int row = (blockIdx.x - 4096) * 4 + (threadIdx.x >> 6);
    int b = row >> 5, t = row & 31;
    const float* src = yg + (size_t)b * 6144 + t;
    float v0 = src[(size_t)lane * 32];
    float v1 = src[(size_t)(lane + 64) * 32];
    float v2 = src[(size_t)(lane + 128) * 32];
    float s = v0 + v1 + v2;
    float s2 = v0 * v0 + v1 * v1 + v2 * v2;
    #pragma unroll
    for (int off = 32; off; off >>= 1) { s += __shfl_xor(s, off); s2 += __shfl_xor(s2, off); }
    float mean = s * (1.f / 192.f);
    float var = s2 * (1.f / 192.f) - mean * mean;
    float inv = rsqrtf(var + 1e-5f);
    ushortT* yr = kvb + (size_t)row * 192;
    yr[lane]       = f2bf((v0 - mean) * inv * kw[lane]       + kb[lane]);
    yr[lane + 64]  = f2bf((v1 - mean) * inv * kw[lane + 64]  + kb[lane + 64]);
    yr[lane + 128] = f2bf((v2 - mean) * inv * kw[lane + 128] + kb[lane + 128]);
  }
}

// ---------------------------------------------------------------------------
// Fused Bahdanau attention; bf16 q/k/v projections, fp32 LDS staging.
// qp/kp PRE-SCALED by 2*log2(e):
// e(q,k) = S0 + sum_d (-2 v_d) * rcp(exp2(qp_d + kp_d) + 1)
// ---------------------------------------------------------------------------
__global__ __launch_bounds__(256) void attn_kernel(
    const ushortT* __restrict__ qpb, const ushortT* __restrict__ kpb,
    const ushortT* __restrict__ vpb, const float* __restrict__ vw,
    ushortT* __restrict__ ctxb) {
  int b = blockIdx.x >> 4;
  int q0 = (blockIdx.x & 15) * 16;
  __shared__ float skp[32 * 132];
  __shared__ float sqp[16 * 132];
  __shared__ float svp[32 * 192];
  __shared__ float se[16][33];
  __shared__ float swm[128];
  __shared__ float sS0;
  int tid = threadIdx.x;

  for (int j = tid; j < 512; j += 256) {
    int k = j >> 4, d8 = j & 15;
    ushort8v v = *(const ushort8v*)&kpb[((size_t)(b * 32 + k)) * 128 + d8 * 8];
    #pragma unroll
    for (int r = 0; r < 8; ++r) skp[k * 132 + d8 * 8 + r] = bf2f(v[r]);
  }
  for (int j = tid; j < 256; j += 256) {
    int qq = j >> 4, d8 = j & 15;
    ushort8v v = *(const ushort8v*)&qpb[((size_t)(b * 256 + q0 + qq)) * 128 + d8 * 8];
    #pragma unroll
    for (int r = 0; r < 8; ++r) sqp[qq * 132 + d8 * 8 + r] = bf2f(v[r]);
  }
  for (int j = tid; j < 768; j += 256) {
    int k = j / 24, c8 = j % 24;
    ushort8v v = *(const ushort8v*)&vpb[((size_t)(b * 32 + k)) * 192 + c8 * 8];
    #pragma unroll
    for (int r = 0; r < 8; ++r) svp[k * 192 + c8 * 8 + r] = bf2f(v[r]);
  }
  if (tid < 128) swm[tid] = -2.f * vw[tid];
  if (tid < 64) {
    float s = vw[tid] + vw[tid + 64];
    #pragma unroll
    for (int off = 32; off; off >>= 1) s += __shfl_xor(s, off);
    if (tid == 0) sS0 = s;
  }
  __syncthreads();

  {
    int qq = tid >> 4, kc = tid & 15;
    const float4* q4 = (const float4*)&sqp[qq * 132];
    const float4* ka = (const float4*)&skp[kc * 132];
    const float4* kb = (const float4*)&skp[(kc + 16) * 132];
    const float4* w4 = (const float4*)swm;
    float S0 = sS0;
    float acc0 = S0, acc1 = S0;
    #pragma unroll 8
    for (int dj = 0; dj < 32; ++dj) {
      float4 qv = q4[dj], k0 = ka[dj], k1 = kb[dj], wv = w4[dj];
      acc0 += wv.x * RCPF(EXP2F(qv.x + k0.x) + 1.f);
      acc0 += wv.y * RCPF(EXP2F(qv.y + k0.y) + 1.f);
      acc0 += wv.z * RCPF(EXP2F(qv.z + k0.z) + 1.f);
      acc0 += wv.w * RCPF(EXP2F(qv.w + k0.w) + 1.f);
      acc1 += wv.x * RCPF(EXP2F(qv.x + k1.x) + 1.f);
      acc1 += wv.y * RCPF(EXP2F(qv.y + k1.y) + 1.f);
      acc1 += wv.z * RCPF(EXP2F(qv.z + k1.z) + 1.f);
      acc1 += wv.w * RCPF(EXP2F(qv.w + k1.w) + 1.f);
    }
    se[qq][kc] = acc0;
    se[qq][kc + 16] = acc1;
  }
  __syncthreads();
  if (tid < 16) {
    float mx = -1e30f;
    for (int k = 0; k < 32; ++k) mx = fmaxf(mx, se[tid][k]);
    float s = 0.f;
    for (int k = 0; k < 32; ++k) { float a = __expf(se[tid][k] - mx); se[tid][k] = a; s += a; }
    float invs = 1.f / s;
    for (int k = 0; k < 32; ++k) se[tid][k] *= invs;
  }
  __syncthreads();
  for (int j = tid; j < 768; j += 256) {
    int qq = j / 48, m4 = j % 48;
    const float* al = se[qq];
    float4 a = {0.f, 0.f, 0.f, 0.f};
    #pragma unroll 8
    for (int k = 0; k < 32; ++k) {
      float wk = al[k];
      float4 v = *(const float4*)&svp[k * 192 + m4 * 4];
      a.x += wk * v.x; a.y += wk * v.y; a.z += wk * v.z; a.w += wk * v.w;
    }
    ushort4 o4 = {f2bf(a.x), f2bf(a.y), f2bf(a.z), f2bf(a.w)};
    *(ushort4*)&ctxb[((size_t)(b * 256 + q0 + qq)) * 192 + m4 * 4] = o4;
  }
}

// ---------------------------------------------------------------------------
// Fused out-proj GEMM + residual + LN + transpose.
// Block: (b, 64-row t tile). A (ctxb) and B (wbo) fragments straight from
// L2 (wbo is 73 KB, resident); fp32 result tile in LDS (49 KB).
// ---------------------------------------------------------------------------
__global__ __launch_bounds__(256) void outproj_ln_kernel(
    const ushortT* __restrict__ ctxb, const ushortT* __restrict__ wbo,
    const float* __restrict__ out_b, const ushortT* __restrict__ qlnb,
    const float* __restrict__ w, const float* __restrict__ bb,
    float* __restrict__ out) {
  int b = blockIdx.x >> 2;
  int t0 = (blockIdx.x & 3) * 64;
  __shared__ float sf[64 * 193];
  int tid = threadIdx.x;
  int wave = tid >> 6, lane = tid & 63, ln15 = lane & 15, kg = lane >> 4;

  const ushortT* Arow = ctxb + ((size_t)(b * 256 + t0)) * 192;

  #pragma unroll
  for (int nc = 0; nc < 3; ++nc) {
    floatx4 acc[4];
    #pragma unroll
    for (int n = 0; n < 4; ++n) acc[n] = (floatx4)0.f;
    #pragma unroll
    for (int k0 = 0; k0 < 192; k0 += 32) {
      bf16x8 afr = *(const bf16x8*)&Arow[((size_t)(wave * 16 + ln15)) * 192 + k0 + kg * 8];
      #pragma unroll
      for (int n = 0; n < 4; ++n) {
        bf16x8 bfr = *(const bf16x8*)&wbo[((size_t)(nc * 64 + n * 16 + ln15)) * 192 + k0 + kg * 8];
        acc[n] = __builtin_amdgcn_mfma_f32_16x16x32_bf16(afr, bfr, acc[n], 0, 0, 0);
      }
    }
    #pragma unroll
    for (int n = 0; n < 4; ++n) {
      int col = nc * 64 + n * 16 + ln15;
      float bv = out_b[col];
      #pragma unroll
      for (int r = 0; r < 4; ++r)
        sf[(wave * 16 + kg * 4 + r) * 193 + col] = acc[n][r] + bv;
    }
  }
  __syncthreads();

  // residual + LN per row (wave handles rows wave, wave+4, ...)
  for (int rr = wave; rr < 64; rr += 4) {
    size_t gb = ((size_t)(b * 256 + t0 + rr)) * 192;
    float v0 = sf[rr * 193 + lane]       + bf2f(qlnb[gb + lane]);
    float v1 = sf[rr * 193 + lane + 64]  + bf2f(qlnb[gb + lane + 64]);
    float v2 = sf[rr * 193 + lane + 128] + bf2f(qlnb[gb + lane + 128]);
    float s = v0 + v1 + v2;
    float s2 = v0 * v0 + v1 * v1 + v2 * v2;
    #pragma unroll
    for (int off = 32; off; off >>= 1) { s += __shfl_xor(s, off); s2 += __shfl_xor(s2, off); }
    float mean = s * (1.f / 192.f);
    float var = s2 * (1.f / 192.f) - mean * mean;
    float inv = rsqrtf(var + 1e-5f);
    sf[rr * 193 + lane]       = (v0 - mean) * inv * w[lane]       + bb[lane];
    sf[rr * 193 + lane + 64]  = (v1 - mean) * inv * w[lane + 64]  + bb[lane + 64];
    sf[rr * 193 + lane + 128] = (v2 - mean) * inv * w[lane + 128] + bb[lane + 128];
  }
  __syncthreads();

  for (int j = tid; j < 192 * 16; j += 256) {
    int m = j >> 4, t4 = j & 15;
    float4 o4;
    o4.x = sf[(t4 * 4 + 0) * 193 + m];
    o4.y = sf[(t4 * 4 + 1) * 193 + m];
    o4.z = sf[(t4 * 4 + 2) * 193 + m];
    o4.w = sf[(t4 * 4 + 3) * 193 + m];
    *(float4*)&out[((size_t)(b * 192 + m)) * 256 + t0 + t4 * 4] = o4;
  }
}

// ---------------------------------------------------------------------------
extern "C" void kernel_launch(void* const* d_in, const int* in_sizes, int n_in,
                              void* d_out, int out_size, void* d_ws, size_t ws_size,
                              hipStream_t stream) {
  (void)in_sizes; (void)n_in; (void)out_size; (void)ws_size;
  const float* x_p     = (const float*)d_in[0];
  const float* y_g     = (const float*)d_in[1];
  const float* conv1_w = (const float*)d_in[2];
  const float* conv1_b = (const float*)d_in[3];
  const float* gamma1  = (const float*)d_in[4];
  const float* beta1   = (const float*)d_in[5];
  const float* conv2_w = (const float*)d_in[6];
  const float* conv2_b = (const float*)d_in[7];
  const float* gamma2  = (const float*)d_in[8];
  const float* beta2   = (const float*)d_in[9];
  const float* conv3_w = (const float*)d_in[10];
  const float* conv3_b = (const float*)d_in[11];
  const float* ln_q_w  = (const float*)d_in[12];
  const float* ln_q_b  = (const float*)d_in[13];
  const float* ln_kv_w = (const float*)d_in[14];
  const float* ln_kv_b = (const float*)d_in[15];
  const float* ln_out_w= (const float*)d_in[16];
  const float* ln_out_b= (const float*)d_in[17];
  const float* Wq      = (const float*)d_in[18];
  const float* Wk      = (const float*)d_in[19];
  const float* v_w     = (const float*)d_in[20];
  const float* Wv      = (const float*)d_in[21];
  const float* out_w   = (const float*)d_in[22];
  const float* out_b   = (const float*)d_in[23];
  float* out = (float*)d_out;
  float* ws  = (float*)d_ws;

  ushortT* t1bf  = (ushortT*)(ws + OFF_T1BF);
  ushortT* x2bf  = (ushortT*)(ws + OFF_X2BF);
  ushortT* t2bf  = (ushortT*)(ws + OFF_T2BF);
  ushortT* x3bf  = (ushortT*)(ws + OFF_X3BF);
  ushortT* qrawb = (ushortT*)(ws + OFF_QRAW);
  ushortT* qlnb  = (ushortT*)(ws + OFF_QLNB);
  ushortT* kvb   = (ushortT*)(ws + OFF_KVB);
  ushortT* qpb   = (ushortT*)(ws + OFF_QP);
  ushortT* kpb   = (ushortT*)(ws + OFF_KP);
  ushortT* vpb   = (ushortT*)(ws + OFF_VP);
  ushortT* wbq   = (ushortT*)(ws + OFF_WBQ);
  ushortT* wbk   = (ushortT*)(ws + OFF_WBK);
  ushortT* wbv   = (ushortT*)(ws + OFF_WBV);
  ushortT* wbo   = (ushortT*)(ws + OFF_WBO);
  ushortT* ctxb  = (ushortT*)(ws + OFF_CTXB);
  ushortT* wt2   = (ushortT*)(ws + OFF_WT2);
  ushortT* wt3   = (ushortT*)(ws + OFF_WT3);
  ushortT* wc1   = (ushortT*)(ws + OFF_WC1);
  ushortT* gb1   = (ushortT*)(ws + OFF_GB1);
  ushortT* gb2   = (ushortT*)(ws + OFF_GB2);

  prep_kernel<<<3152, 256, 0, stream>>>(conv2_w, wt2, conv3_w, wt3, conv1_w, wc1,
                                        Wq, wbq, Wk, wbk, Wv, wbv, out_w, wbo,
                                        gamma1, gb1, gamma2, gb2);
  conv1_mfma_kernel<<<256, 256, 0, stream>>>(x_p, wc1, conv1_b, t1bf);
  gdn_mfma_kernel<<<1024, 256, 0, stream>>>(t1bf, gb1, beta1, x2bf, 1024, 16, 1);
  conv_mfma_kernel<0><<<512, 256, 0, stream>>>(x2bf, wt2, conv2_b, t2bf);
  gdn_mfma_kernel<<<256, 256, 0, stream>>>(t2bf, gb2, beta2, x3bf, 256, 4, 0);
  conv_mfma_kernel<1><<<768, 256, 0, stream>>>(x3bf, wt3, conv3_b, qrawb);
  ln_all_kernel<<<4608, 256, 0, stream>>>(qrawb, ln_q_w, ln_q_b, qlnb,
                                          y_g, ln_kv_w, ln_kv_b, kvb);
  gemm_qkv_kernel<<<336, 256, 0, stream>>>(qlnb, kvb, wbq, wbk, wbv,
                                           qpb, kpb, vpb);
  attn_kernel<<<1024, 256, 0, stream>>>(qpb, kpb, vpb, v_w, ctxb);
  outproj_ln_kernel<<<256, 256, 0, stream>>>(ctxb, wbo, out_b, qlnb,
                                             ln_out_w, ln_out_b, out);
}